// Round 14
// baseline (301.859 us; speedup 1.0000x reference)
//
#include <hip/hip_runtime.h>

#define N_NODES 50000
#define N_EDGES 800000
#define EPS 1e-5f

typedef __attribute__((ext_vector_type(8))) short bf16x8;
typedef __attribute__((ext_vector_type(4))) float f32x4;
typedef __attribute__((ext_vector_type(4))) unsigned short us4;

__device__ __forceinline__ unsigned short f2b(float f) {
    union { float f; unsigned int u; } v; v.f = f;
    unsigned int r = v.u + 0x7fffu + ((v.u >> 16) & 1u);
    return (unsigned short)(r >> 16);
}
__device__ __forceinline__ float b2f(unsigned short b) {
    union { unsigned int u; float f; } v; v.u = ((unsigned int)b) << 16;
    return v.f;
}

// Sorted-domain pipeline (r12) + XCD-pinned chunk-major gathers (r8) + deep-pipelined
// branch-free gather loop (r13). r14: each node's slot range split across 2 lane-groups
// (8 lanes/node: group0 slots [0,h), group1 [h,nslots)) -> serial chain halved, groups
// combined with one shfl_xor(4). Contiguous per-group slots keep the unroll-x2 pipeline.

#define RED_BUCKETS 64
#define RED_FLOATS_PER_LAYER (RED_BUCKETS * 16)

#define CV_NX (N_NODES * 128 / 4)
#define CV_N0 (256 * 128 / 4)
#define CV_N1 (256 * 256 / 4)
#define CV_N2 (128 * 256 / 4)

// ---------------- prep: zeros + weight converts ----------------

__global__ void prep_kernel(const float* __restrict__ W0, const float* __restrict__ W1,
                            const float* __restrict__ W2,
                            unsigned short* __restrict__ wb0, unsigned short* __restrict__ wb1,
                            unsigned short* __restrict__ wb2,
                            int* __restrict__ deg, int* __restrict__ fill,
                            int* __restrict__ hist, float* __restrict__ red) {
    int i = blockIdx.x * 256 + threadIdx.x;
    if (i < N_NODES) { deg[i] = 0; fill[i] = 0; }
    if (i < 256) hist[i] = 0;
    if (i < 3 * RED_FLOATS_PER_LAYER) red[i] = 0.f;
    int j = i;
    const float* s;
    unsigned short* d;
    if (j < CV_N0) { s = W0; d = wb0; }
    else if ((j -= CV_N0) < CV_N1) { s = W1; d = wb1; }
    else if ((j -= CV_N1) < CV_N2) { s = W2; d = wb2; }
    else return;
    float4 v = reinterpret_cast<const float4*>(s)[j];
    us4 o;
    o[0] = f2b(v.x); o[1] = f2b(v.y); o[2] = f2b(v.z); o[3] = f2b(v.w);
    reinterpret_cast<us4*>(d)[j] = o;
}

// ---------------- CSR build (sorted domain) ----------------

__global__ void count_kernel(const int* __restrict__ dst, int* __restrict__ deg, int e) {
    for (int i = blockIdx.x * blockDim.x + threadIdx.x; i < e; i += gridDim.x * blockDim.x)
        atomicAdd(&deg[dst[i]], 1);
}

__global__ void histo_kernel(const int* __restrict__ deg, float* __restrict__ dinv,
                             int* __restrict__ hist, int n) {
    __shared__ int lh[256];
    lh[threadIdx.x] = 0;
    __syncthreads();
    int i = blockIdx.x * 256 + threadIdx.x;
    if (i < n) {
        int v = deg[i];
        dinv[i] = rsqrtf((float)(v + 1));  // +1 self-loop
        atomicAdd(&lh[v < 255 ? v : 255], 1);
    }
    __syncthreads();
    if (lh[threadIdx.x] > 0) atomicAdd(&hist[threadIdx.x], lh[threadIdx.x]);
}

__global__ void scan2_kernel(const int* __restrict__ hist, int* __restrict__ binpre,
                             int* __restrict__ binfill, int* __restrict__ edgepre) {
    __shared__ int sm[256];
    int t = threadIdx.x;
    int h = hist[t];
    sm[t] = h;
    __syncthreads();
    #pragma unroll
    for (int d = 1; d < 256; d <<= 1) {
        int x = (t >= d) ? sm[t - d] : 0;
        __syncthreads();
        sm[t] += x;
        __syncthreads();
    }
    int npre = (t > 0) ? sm[t - 1] : 0;
    binpre[t] = npre;
    binfill[t] = npre;
    __syncthreads();
    sm[t] = h * t;
    __syncthreads();
    #pragma unroll
    for (int d = 1; d < 256; d <<= 1) {
        int x = (t >= d) ? sm[t - d] : 0;
        __syncthreads();
        sm[t] += x;
        __syncthreads();
    }
    edgepre[t] = (t > 0) ? sm[t - 1] : 0;
}

__global__ void permute_kernel(const int* __restrict__ deg, const float* __restrict__ dinv,
                               const int* __restrict__ binpre, int* __restrict__ binfill,
                               const int* __restrict__ edgepre,
                               int* __restrict__ perm, int* __restrict__ iperm,
                               float* __restrict__ dinv2s, int* __restrict__ soff, int n) {
    __shared__ int lhist[256];
    __shared__ int lbase[256];
    int t = threadIdx.x;
    lhist[t] = 0;
    __syncthreads();
    int i = blockIdx.x * 256 + t;
    int b = 0, lpos = 0;
    bool act = i < n;
    if (act) {
        int v = deg[i];
        b = v < 255 ? v : 255;
        lpos = atomicAdd(&lhist[b], 1);
    }
    __syncthreads();
    if (lhist[t] > 0) lbase[t] = atomicAdd(&binfill[t], lhist[t]);
    __syncthreads();
    if (act) {
        int p = lbase[b] + lpos;
        perm[p] = i;
        iperm[i] = p;
        float di = dinv[i];
        dinv2s[p] = di * di;
        soff[p] = edgepre[b] + (p - binpre[b]) * b;
    }
    if (blockIdx.x == 0 && t == 0) soff[n] = N_EDGES;
}

__global__ void convert_x_kernel(const float* __restrict__ x0, const int* __restrict__ perm,
                                 unsigned short* __restrict__ xb) {
    int j = blockIdx.x * 256 + threadIdx.x;
    if (j >= CV_NX) return;
    int p = j >> 5;
    int c4 = j & 31;
    int orig = perm[p];
    float4 v = reinterpret_cast<const float4*>(x0)[orig * 32 + c4];
    int col0 = c4 * 4;
    us4 o;
    o[0] = f2b(v.x); o[1] = f2b(v.y); o[2] = f2b(v.z); o[3] = f2b(v.w);
    *reinterpret_cast<us4*>(xb + ((size_t)(col0 >> 5) * N_NODES + p) * 32 + (col0 & 31)) = o;
}

__global__ void scatter_kernel(const int* __restrict__ src, const int* __restrict__ dst,
                               const int* __restrict__ soff, int* __restrict__ fill,
                               const float* __restrict__ dinv, const int* __restrict__ iperm,
                               unsigned int* __restrict__ epack, int e) {
    for (int i = blockIdx.x * blockDim.x + threadIdx.x; i < e; i += gridDim.x * blockDim.x) {
        int d = dst[i];
        int s = src[i];
        int pd = iperm[d];
        int pos = soff[pd] + atomicAdd(&fill[pd], 1);
        epack[pos] = ((unsigned int)f2b(dinv[s] * dinv[d]) << 16) | (unsigned int)iperm[s];
    }
}

// ---------------- GEMM body (chunk-major, sorted domain) ----------------

template<int BN, bool TRANSFORM, bool ADD_BIAS, bool FUSE_RED>
__device__ __forceinline__ void gemm_body(
    const unsigned short* __restrict__ Xin, const unsigned short* __restrict__ Wb,
    const float* __restrict__ bias, const float* __restrict__ redin,
    const float* __restrict__ gw, const float* __restrict__ bw,
    const float* __restrict__ asl, float* __restrict__ redout,
    unsigned short* __restrict__ Hout, int M, int K, float inv_count) {
    constexpr int FR_N = BN / 64;
    __shared__ unsigned short xs[2][64 * 32];
    int tid = threadIdx.x;
    int wid = tid >> 6, lane = tid & 63;
    int l16 = lane & 15, kg = lane >> 4;
    int srow = tid >> 2, sblk = tid & 3;
    int m0 = blockIdx.x * 64;
    int colbase = wid * (BN / 4);

    float mu = 0.f, rstd = 0.f, alpha = 0.f;
    if (TRANSFORM) {
        float s = redin[lane * 16], s2 = redin[lane * 16 + 1];
        #pragma unroll
        for (int off = 1; off < 64; off <<= 1) { s += __shfl_xor(s, off); s2 += __shfl_xor(s2, off); }
        mu = s * inv_count;
        rstd = rsqrtf(s2 * inv_count - mu * mu + EPS);
        alpha = asl[0];
    }

    int gmr = m0 + srow;
    bool inm = (gmr < M);
    const unsigned short* xrow = Xin + (size_t)gmr * 32 + sblk * 8;
    unsigned short* xdst = &xs[0][srow * 32 + ((sblk ^ (srow & 3)) * 8)];

    auto stage = [&](int k0, int buf) {
        bf16x8 xv = {};
        if (inm) {
            bf16x8 u = *reinterpret_cast<const bf16x8*>(xrow + (size_t)(k0 >> 5) * N_NODES * 32);
            if (TRANSFORM) {
                int f0 = k0 + sblk * 8;
                float ga[8], ba[8];
                *reinterpret_cast<float4*>(&ga[0]) = *reinterpret_cast<const float4*>(gw + f0);
                *reinterpret_cast<float4*>(&ga[4]) = *reinterpret_cast<const float4*>(gw + f0 + 4);
                *reinterpret_cast<float4*>(&ba[0]) = *reinterpret_cast<const float4*>(bw + f0);
                *reinterpret_cast<float4*>(&ba[4]) = *reinterpret_cast<const float4*>(bw + f0 + 4);
                #pragma unroll
                for (int i = 0; i < 8; ++i) {
                    float A = rstd * ga[i];
                    float B = ba[i] - mu * A;
                    float v = fmaf(b2f((unsigned short)u[i]), A, B);
                    v = fmaf(fminf(v, 0.f), alpha - 1.0f, v);
                    xv[i] = (short)f2b(v);
                }
            } else {
                xv = u;
            }
        }
        *reinterpret_cast<bf16x8*>(xdst + buf * (64 * 32)) = xv;
    };

    stage(0, 0);
    f32x4 acc[4][FR_N] = {};
    int nsteps = K / 32;
    for (int s = 0; s < nsteps; ++s) {
        __syncthreads();
        int k0 = s * 32;
        if (s + 1 < nsteps) stage(k0 + 32, (s + 1) & 1);
        bf16x8 b[FR_N];
        #pragma unroll
        for (int j = 0; j < FR_N; ++j)
            b[j] = *reinterpret_cast<const bf16x8*>(
                Wb + (size_t)(colbase + j * 16 + l16) * K + k0 + kg * 8);
        const unsigned short* xbuf = xs[s & 1];
        bf16x8 a[4];
        #pragma unroll
        for (int i = 0; i < 4; ++i) {
            int ar = i * 16 + l16;
            a[i] = *reinterpret_cast<const bf16x8*>(xbuf + ar * 32 + ((kg ^ (ar & 3)) * 8));
        }
        #pragma unroll
        for (int i = 0; i < 4; ++i)
            #pragma unroll
            for (int j = 0; j < FR_N; ++j)
                acc[i][j] = __builtin_amdgcn_mfma_f32_16x16x32_bf16(b[j], a[i], acc[i][j], 0, 0, 0);
    }

    float bsel[FR_N][4];
    if (ADD_BIAS) {
        #pragma unroll
        for (int j = 0; j < FR_N; ++j)
            *reinterpret_cast<float4*>(bsel[j]) =
                *reinterpret_cast<const float4*>(bias + colbase + j * 16 + kg * 4);
    }
    float s = 0.f, s2 = 0.f;
    #pragma unroll
    for (int i = 0; i < 4; ++i) {
        int row = m0 + i * 16 + l16;
        if (row < M) {
            #pragma unroll
            for (int j = 0; j < FR_N; ++j) {
                int col = colbase + j * 16 + kg * 4;
                us4 o;
                #pragma unroll
                for (int r = 0; r < 4; ++r) {
                    float v = acc[i][j][r] + (ADD_BIAS ? bsel[j][r] : 0.f);
                    if (FUSE_RED) { s += v; s2 += v * v; }
                    o[r] = f2b(v);
                }
                *reinterpret_cast<us4*>(
                    Hout + ((size_t)(col >> 5) * N_NODES + row) * 32 + (col & 31)) = o;
            }
        }
    }
    if (FUSE_RED) {
        #pragma unroll
        for (int off = 1; off < 64; off <<= 1) { s += __shfl_xor(s, off); s2 += __shfl_xor(s2, off); }
        if (lane == 0) {
            int bkt = (blockIdx.x & (RED_BUCKETS - 1)) * 16;
            atomicAdd(&redout[bkt], s);
            atomicAdd(&redout[bkt + 1], s2);
        }
    }
}

// ---------------- aggregation: sorted domain, XCD-pinned chunk, split-slot pipelined ----------
// 8 lanes/node = 2 slot-groups x 4 lanes (16B each). Group 0 handles slots [0,h),
// group 1 [h,nslots) (h = ceil(nslots/2)) — contiguous per group so the unroll-x2
// row-prefetch pipeline survives. Groups combined with shfl_xor(4). Serial chain halved.

template<int COLS, bool ADD_BIAS, bool FUSE_RED>
__device__ __forceinline__ void agg_body(
    const unsigned short* __restrict__ Hb, const int* __restrict__ soff,
    const unsigned int* __restrict__ epack, const float* __restrict__ dinv2s,
    const float* __restrict__ bias, unsigned short* __restrict__ Y,
    float* __restrict__ red) {
    constexpr int CHUNKS = COLS / 32;
    int chunk = blockIdx.x % CHUNKS;
    int nodeblk = blockIdx.x / CHUNKS;
    int t = threadIdx.x;
    int p = nodeblk * 32 + (t >> 3);      // 32 nodes per 256-thread block
    int g = (t >> 2) & 1;                 // slot group 0/1
    int rl = t & 3;                       // 16B slot within 64B row slice
    bool active = p < N_NODES;
    int pc = active ? p : (N_NODES - 1);
    const unsigned short* base = Hb + (size_t)chunk * N_NODES * 32 + rl * 8;
    int s0 = soff[pc], s1 = soff[pc + 1];
    float wself = active ? dinv2s[pc] : 0.f;
    int nslots = active ? (1 + s1 - s0) : 0;
    int h = (nslots + 1) >> 1;
    int jstart = g ? h : 0;
    int jend = g ? nslots : h;
    int cnt = jend - jstart;

    // wave-max group count (degree-sorted -> nearly uniform)
    int cmax = cnt;
    #pragma unroll
    for (int off = 1; off < 64; off <<= 1) cmax = max(cmax, __shfl_xor(cmax, off));

    auto eload = [&](int j) -> unsigned int {
        int idx = s0 + j - 1;
        idx = idx < 0 ? 0 : (idx >= N_EDGES ? N_EDGES - 1 : idx);
        return epack[idx];
    };
    auto decode = [&](unsigned int u, int j, float& w, int& s) {
        if (j == 0) { w = wself; s = pc; }
        else if (j < jend) { w = b2f((unsigned short)(u >> 16)); s = (int)(u & 0xffffu); }
        else { w = 0.f; s = pc; }
    };
    auto rowld = [&](int s) -> bf16x8 {
        return *reinterpret_cast<const bf16x8*>(base + (size_t)s * 32);
    };

    float acc[8] = {};
    if (cmax > 0) {
        int j0 = jstart;
        unsigned int ua = eload(j0), ub = eload(j0 + 1);
        float w0, w1; int sa, sb;
        decode(ua, j0, w0, sa);
        decode(ub, j0 + 1, w1, sb);
        bf16x8 v0 = rowld(sa), v1 = rowld(sb);
        unsigned int u2 = eload(j0 + 2), u3 = eload(j0 + 3);
        for (int i = 0; i < cmax; i += 2) {
            int j = j0 + i;
            float w2, w3; int s2, s3;
            decode(u2, j + 2, w2, s2);
            decode(u3, j + 3, w3, s3);
            bf16x8 v2 = rowld(s2), v3 = rowld(s3);   // issue 2 ahead
            unsigned int u4 = eload(j + 4), u5 = eload(j + 5);
            #pragma unroll
            for (int q = 0; q < 8; ++q) acc[q] += w0 * b2f((unsigned short)v0[q]);
            #pragma unroll
            for (int q = 0; q < 8; ++q) acc[q] += w1 * b2f((unsigned short)v1[q]);
            w0 = w2; v0 = v2; w1 = w3; v1 = v3; u2 = u4; u3 = u5;
        }
    }

    // combine the two slot groups (lanes differing in bit 2)
    #pragma unroll
    for (int q = 0; q < 8; ++q) acc[q] += __shfl_xor(acc[q], 4);

    if (ADD_BIAS && active && g == 0) {
        #pragma unroll
        for (int q = 0; q < 8; ++q) acc[q] += bias[chunk * 32 + rl * 8 + q];
    }
    if (FUSE_RED) {
        float s = 0.f, s2 = 0.f;
        if (g == 0) {
            #pragma unroll
            for (int q = 0; q < 8; ++q) { s += acc[q]; s2 += acc[q] * acc[q]; }
        }
        #pragma unroll
        for (int off = 1; off < 64; off <<= 1) { s += __shfl_xor(s, off); s2 += __shfl_xor(s2, off); }
        if ((t & 63) == 0) {
            int bkt = (blockIdx.x & (RED_BUCKETS - 1)) * 16;
            atomicAdd(&red[bkt], s);
            atomicAdd(&red[bkt + 1], s2);
        }
    }
    if (active && g == 0) {
        bf16x8 o;
        #pragma unroll
        for (int q = 0; q < 8; ++q) o[q] = (short)f2b(acc[q]);
        __builtin_nontemporal_store(
            o, reinterpret_cast<bf16x8*>(Y + ((size_t)chunk * N_NODES + p) * 32 + rl * 8));
    }
}

// ---------------- distinctly-named wrappers ----------------

__global__ __launch_bounds__(256) void gemm_l0(const unsigned short* X, const unsigned short* W,
                                               const float* bias, float* redout,
                                               unsigned short* H, int M, int K, float ic) {
    gemm_body<256, false, true, true>(X, W, bias, nullptr, nullptr, nullptr, nullptr, redout, H, M, K, ic);
}
__global__ __launch_bounds__(256) void gemm_l1(const unsigned short* X, const unsigned short* W,
                                               const float* redin, const float* gw, const float* bw,
                                               const float* asl, unsigned short* H, int M, int K, float ic) {
    gemm_body<256, true, false, false>(X, W, nullptr, redin, gw, bw, asl, nullptr, H, M, K, ic);
}
__global__ __launch_bounds__(256) void gemm_l2(const unsigned short* X, const unsigned short* W,
                                               const float* redin, const float* gw, const float* bw,
                                               const float* asl, unsigned short* H, int M, int K, float ic) {
    gemm_body<128, true, false, false>(X, W, nullptr, redin, gw, bw, asl, nullptr, H, M, K, ic);
}
__global__ void agg_l0(const unsigned short* Hb, const int* soff, const unsigned int* ep,
                       const float* dinv2s, unsigned short* Y) {
    agg_body<128, false, false>(Hb, soff, ep, dinv2s, nullptr, Y, nullptr);
}
__global__ void agg_l1(const unsigned short* Hb, const int* soff, const unsigned int* ep,
                       const float* dinv2s, const float* bias, unsigned short* Y, float* red) {
    agg_body<256, true, true>(Hb, soff, ep, dinv2s, bias, Y, red);
}
__global__ void agg_l2(const unsigned short* Hb, const int* soff, const unsigned int* ep,
                       const float* dinv2s, const float* bias, unsigned short* Y, float* red) {
    agg_body<128, true, true>(Hb, soff, ep, dinv2s, bias, Y, red);
}

// ---------------- final LN + PReLU: original-domain loop, gathered sorted reads ----------------

__global__ void norm_final(const unsigned short* __restrict__ Yb, const int* __restrict__ iperm,
                           const float* __restrict__ red,
                           const float* __restrict__ g, const float* __restrict__ be,
                           const float* __restrict__ a, float* __restrict__ X,
                           float inv_count) {
    int lane = threadIdx.x & 63;
    float s = red[lane * 16], s2 = red[lane * 16 + 1];
    #pragma unroll
    for (int off = 1; off < 64; off <<= 1) { s += __shfl_xor(s, off); s2 += __shfl_xor(s2, off); }
    float mu = s * inv_count;
    float rstd = rsqrtf(s2 * inv_count - mu * mu + EPS);
    float alpha = a[0];
    int total = N_NODES * 16;
    for (int i = blockIdx.x * blockDim.x + threadIdx.x; i < total; i += gridDim.x * blockDim.x) {
        int n = i >> 4;
        int r = i & 15;
        int f0 = r * 8;
        int p = iperm[n];
        bf16x8 v = *reinterpret_cast<const bf16x8*>(
            Yb + ((size_t)(f0 >> 5) * N_NODES + p) * 32 + (f0 & 31));
        float o[8];
        #pragma unroll
        for (int j = 0; j < 8; ++j) {
            float t = (b2f((unsigned short)v[j]) - mu) * rstd * g[f0 + j] + be[f0 + j];
            o[j] = t >= 0.f ? t : alpha * t;
        }
        float* xp = X + (size_t)n * 128 + f0;
        *reinterpret_cast<float4*>(xp) = make_float4(o[0], o[1], o[2], o[3]);
        *reinterpret_cast<float4*>(xp + 4) = make_float4(o[4], o[5], o[6], o[7]);
    }
}

// ---------------- launch ----------------

extern "C" void kernel_launch(void* const* d_in, const int* in_sizes, int n_in,
                              void* d_out, int out_size, void* d_ws, size_t ws_size,
                              hipStream_t stream) {
    const float* x0 = (const float*)d_in[0];
    const int* ei = (const int*)d_in[1];
    const float* W[3] = {(const float*)d_in[2], (const float*)d_in[7], (const float*)d_in[12]};
    const float* bb[3] = {(const float*)d_in[3], (const float*)d_in[8], (const float*)d_in[13]};
    const float* gg[3] = {(const float*)d_in[4], (const float*)d_in[9], (const float*)d_in[14]};
    const float* be[3] = {(const float*)d_in[5], (const float*)d_in[10], (const float*)d_in[15]};
    const float* aa[3] = {(const float*)d_in[6], (const float*)d_in[11], (const float*)d_in[16]};

    char* ws = (char*)d_ws;
    size_t o = 0;
    auto alloc = [&](size_t bytes) {
        void* p = ws + o;
        o = (o + bytes + 255) & ~(size_t)255;
        return p;
    };
    int* deg = (int*)alloc(N_NODES * 4);
    int* fill = (int*)alloc(N_NODES * 4);
    int* soff = (int*)alloc((N_NODES + 1) * 4);
    unsigned int* epack = (unsigned int*)alloc((size_t)N_EDGES * 4);
    float* dinv = (float*)alloc(N_NODES * 4);
    float* dinv2s = (float*)alloc(N_NODES * 4);
    int* hist = (int*)alloc(256 * 4);
    int* binpre = (int*)alloc(256 * 4);
    int* binfill = (int*)alloc(256 * 4);
    int* edgepre = (int*)alloc(256 * 4);
    int* perm = (int*)alloc(N_NODES * 4);
    int* iperm = (int*)alloc(N_NODES * 4);
    float* red = (float*)alloc(3 * RED_FLOATS_PER_LAYER * 4);
    unsigned short* Wb0 = (unsigned short*)alloc(256 * 128 * 2);
    unsigned short* Wb1 = (unsigned short*)alloc(256 * 256 * 2);
    unsigned short* Wb2 = (unsigned short*)alloc(128 * 256 * 2);
    unsigned short* xb = (unsigned short*)alloc((size_t)N_NODES * 128 * 2);
    unsigned short* hb = (unsigned short*)alloc((size_t)N_NODES * 256 * 2);
    unsigned short* yb = (unsigned short*)alloc((size_t)N_NODES * 256 * 2);

    const int* e_src = ei;
    const int* e_dst = ei + N_EDGES;
    int nb = (N_NODES + 255) / 256;  // 196

    prep_kernel<<<nb, 256, 0, stream>>>(W[0], W[1], W[2], Wb0, Wb1, Wb2, deg, fill, hist, red);
    count_kernel<<<2048, 256, 0, stream>>>(e_dst, deg, N_EDGES);
    histo_kernel<<<nb, 256, 0, stream>>>(deg, dinv, hist, N_NODES);
    scan2_kernel<<<1, 256, 0, stream>>>(hist, binpre, binfill, edgepre);
    permute_kernel<<<nb, 256, 0, stream>>>(deg, dinv, binpre, binfill, edgepre,
                                           perm, iperm, dinv2s, soff, N_NODES);
    convert_x_kernel<<<(CV_NX + 255) / 256, 256, 0, stream>>>(x0, perm, xb);
    scatter_kernel<<<2048, 256, 0, stream>>>(e_src, e_dst, soff, fill, dinv, iperm,
                                             epack, N_EDGES);

    int gm = (N_NODES + 63) / 64;      // 782
    int nb32 = (N_NODES + 31) / 32;    // 1563 node-blocks for agg
    float ic256 = 1.0f / (N_NODES * 256.0f);
    float ic128 = 1.0f / (N_NODES * 128.0f);

    // ---- Layer 0 ----
    agg_l0<<<nb32 * 4, 256, 0, stream>>>(xb, soff, epack, dinv2s, hb);
    gemm_l0<<<gm, 256, 0, stream>>>(hb, Wb0, bb[0], red + 0, yb, N_NODES, 128, ic256);

    // ---- Layer 1 ----
    gemm_l1<<<gm, 256, 0, stream>>>(yb, Wb1, red + 0, gg[0], be[0], aa[0], hb, N_NODES, 256, ic256);
    agg_l1<<<nb32 * 8, 256, 0, stream>>>(hb, soff, epack, dinv2s, bb[1], yb,
                                         red + RED_FLOATS_PER_LAYER);

    // ---- Layer 2 ----
    gemm_l2<<<gm, 256, 0, stream>>>(yb, Wb2, red + RED_FLOATS_PER_LAYER, gg[1], be[1], aa[1], hb,
                                    N_NODES, 256, ic256);
    agg_l2<<<nb32 * 4, 256, 0, stream>>>(hb, soff, epack, dinv2s, bb[2], yb,
                                         red + 2 * RED_FLOATS_PER_LAYER);

    // ---- final LN + PReLU -> d_out f32 (original domain) ----
    norm_final<<<2048, 256, 0, stream>>>(yb, iperm, red + 2 * RED_FLOATS_PER_LAYER,
                                         gg[2], be[2], aa[2], (float*)d_out, ic128);
}

// Round 15
// 294.340 us; speedup vs baseline: 1.0255x; 1.0255x over previous
//
#include <hip/hip_runtime.h>

#define N_NODES 50000
#define N_EDGES 800000
#define EPS 1e-5f

typedef __attribute__((ext_vector_type(8))) short bf16x8;
typedef __attribute__((ext_vector_type(4))) float f32x4;
typedef __attribute__((ext_vector_type(2))) float f32x2;
typedef __attribute__((ext_vector_type(4))) unsigned int u32x4;
typedef __attribute__((ext_vector_type(4))) unsigned short us4;

__device__ __forceinline__ unsigned short f2b(float f) {
    union { float f; unsigned int u; } v; v.f = f;
    unsigned int r = v.u + 0x7fffu + ((v.u >> 16) & 1u);
    return (unsigned short)(r >> 16);
}
__device__ __forceinline__ float b2f(unsigned short b) {
    union { unsigned int u; float f; } v; v.u = ((unsigned int)b) << 16;
    return v.f;
}

// Sorted-domain pipeline (r12) + XCD-pinned chunk-major gathers (r8) + r13's 4-lane/node
// deep-pipelined gather (r14's slot-split was VALU-regressive; reverted). r15 = VALU diet:
// padded epack (no clamps), peeled self-loop (no j==0 branch; w-extract = 1 AND),
// 32-bit saddr offsets (no 64-bit addr math), f32x2 packed accumulate (v_pk_fma_f32).

#define RED_BUCKETS 64
#define RED_FLOATS_PER_LAYER (RED_BUCKETS * 16)

#define CV_NX (N_NODES * 128 / 4)
#define CV_N0 (256 * 128 / 4)
#define CV_N1 (256 * 256 / 4)
#define CV_N2 (128 * 256 / 4)

// ---------------- prep: zeros + weight converts + epack pad ----------------

__global__ void prep_kernel(const float* __restrict__ W0, const float* __restrict__ W1,
                            const float* __restrict__ W2,
                            unsigned short* __restrict__ wb0, unsigned short* __restrict__ wb1,
                            unsigned short* __restrict__ wb2,
                            int* __restrict__ deg, int* __restrict__ fill,
                            int* __restrict__ hist, float* __restrict__ red,
                            unsigned int* __restrict__ epack) {
    int i = blockIdx.x * 256 + threadIdx.x;
    if (i < N_NODES) { deg[i] = 0; fill[i] = 0; }
    if (i < 256) hist[i] = 0;
    if (i < 3 * RED_FLOATS_PER_LAYER) red[i] = 0.f;
    if (i < 64) epack[N_EDGES + i] = 0u;  // pad: decodes to w=0, src=0 (safe)
    int j = i;
    const float* s;
    unsigned short* d;
    if (j < CV_N0) { s = W0; d = wb0; }
    else if ((j -= CV_N0) < CV_N1) { s = W1; d = wb1; }
    else if ((j -= CV_N1) < CV_N2) { s = W2; d = wb2; }
    else return;
    float4 v = reinterpret_cast<const float4*>(s)[j];
    us4 o;
    o[0] = f2b(v.x); o[1] = f2b(v.y); o[2] = f2b(v.z); o[3] = f2b(v.w);
    reinterpret_cast<us4*>(d)[j] = o;
}

// ---------------- CSR build (sorted domain) ----------------

__global__ void count_kernel(const int* __restrict__ dst, int* __restrict__ deg, int e) {
    for (int i = blockIdx.x * blockDim.x + threadIdx.x; i < e; i += gridDim.x * blockDim.x)
        atomicAdd(&deg[dst[i]], 1);
}

__global__ void histo_kernel(const int* __restrict__ deg, float* __restrict__ dinv,
                             int* __restrict__ hist, int n) {
    __shared__ int lh[256];
    lh[threadIdx.x] = 0;
    __syncthreads();
    int i = blockIdx.x * 256 + threadIdx.x;
    if (i < n) {
        int v = deg[i];
        dinv[i] = rsqrtf((float)(v + 1));  // +1 self-loop
        atomicAdd(&lh[v < 255 ? v : 255], 1);
    }
    __syncthreads();
    if (lh[threadIdx.x] > 0) atomicAdd(&hist[threadIdx.x], lh[threadIdx.x]);
}

__global__ void scan2_kernel(const int* __restrict__ hist, int* __restrict__ binpre,
                             int* __restrict__ binfill, int* __restrict__ edgepre) {
    __shared__ int sm[256];
    int t = threadIdx.x;
    int h = hist[t];
    sm[t] = h;
    __syncthreads();
    #pragma unroll
    for (int d = 1; d < 256; d <<= 1) {
        int x = (t >= d) ? sm[t - d] : 0;
        __syncthreads();
        sm[t] += x;
        __syncthreads();
    }
    int npre = (t > 0) ? sm[t - 1] : 0;
    binpre[t] = npre;
    binfill[t] = npre;
    __syncthreads();
    sm[t] = h * t;
    __syncthreads();
    #pragma unroll
    for (int d = 1; d < 256; d <<= 1) {
        int x = (t >= d) ? sm[t - d] : 0;
        __syncthreads();
        sm[t] += x;
        __syncthreads();
    }
    edgepre[t] = (t > 0) ? sm[t - 1] : 0;
}

__global__ void permute_kernel(const int* __restrict__ deg, const float* __restrict__ dinv,
                               const int* __restrict__ binpre, int* __restrict__ binfill,
                               const int* __restrict__ edgepre,
                               int* __restrict__ perm, int* __restrict__ iperm,
                               float* __restrict__ dinv2s, int* __restrict__ soff, int n) {
    __shared__ int lhist[256];
    __shared__ int lbase[256];
    int t = threadIdx.x;
    lhist[t] = 0;
    __syncthreads();
    int i = blockIdx.x * 256 + t;
    int b = 0, lpos = 0;
    bool act = i < n;
    if (act) {
        int v = deg[i];
        b = v < 255 ? v : 255;
        lpos = atomicAdd(&lhist[b], 1);
    }
    __syncthreads();
    if (lhist[t] > 0) lbase[t] = atomicAdd(&binfill[t], lhist[t]);
    __syncthreads();
    if (act) {
        int p = lbase[b] + lpos;
        perm[p] = i;
        iperm[i] = p;
        float di = dinv[i];
        dinv2s[p] = di * di;
        soff[p] = edgepre[b] + (p - binpre[b]) * b;
    }
    if (blockIdx.x == 0 && t == 0) soff[n] = N_EDGES;
}

__global__ void convert_x_kernel(const float* __restrict__ x0, const int* __restrict__ perm,
                                 unsigned short* __restrict__ xb) {
    int j = blockIdx.x * 256 + threadIdx.x;
    if (j >= CV_NX) return;
    int p = j >> 5;
    int c4 = j & 31;
    int orig = perm[p];
    float4 v = reinterpret_cast<const float4*>(x0)[orig * 32 + c4];
    int col0 = c4 * 4;
    us4 o;
    o[0] = f2b(v.x); o[1] = f2b(v.y); o[2] = f2b(v.z); o[3] = f2b(v.w);
    *reinterpret_cast<us4*>(xb + ((size_t)(col0 >> 5) * N_NODES + p) * 32 + (col0 & 31)) = o;
}

__global__ void scatter_kernel(const int* __restrict__ src, const int* __restrict__ dst,
                               const int* __restrict__ soff, int* __restrict__ fill,
                               const float* __restrict__ dinv, const int* __restrict__ iperm,
                               unsigned int* __restrict__ epack, int e) {
    for (int i = blockIdx.x * blockDim.x + threadIdx.x; i < e; i += gridDim.x * blockDim.x) {
        int d = dst[i];
        int s = src[i];
        int pd = iperm[d];
        int pos = soff[pd] + atomicAdd(&fill[pd], 1);
        epack[pos] = ((unsigned int)f2b(dinv[s] * dinv[d]) << 16) | (unsigned int)iperm[s];
    }
}

// ---------------- GEMM body (chunk-major, sorted domain) ----------------

template<int BN, bool TRANSFORM, bool ADD_BIAS, bool FUSE_RED>
__device__ __forceinline__ void gemm_body(
    const unsigned short* __restrict__ Xin, const unsigned short* __restrict__ Wb,
    const float* __restrict__ bias, const float* __restrict__ redin,
    const float* __restrict__ gw, const float* __restrict__ bw,
    const float* __restrict__ asl, float* __restrict__ redout,
    unsigned short* __restrict__ Hout, int M, int K, float inv_count) {
    constexpr int FR_N = BN / 64;
    __shared__ unsigned short xs[2][64 * 32];
    int tid = threadIdx.x;
    int wid = tid >> 6, lane = tid & 63;
    int l16 = lane & 15, kg = lane >> 4;
    int srow = tid >> 2, sblk = tid & 3;
    int m0 = blockIdx.x * 64;
    int colbase = wid * (BN / 4);

    float mu = 0.f, rstd = 0.f, alpha = 0.f;
    if (TRANSFORM) {
        float s = redin[lane * 16], s2 = redin[lane * 16 + 1];
        #pragma unroll
        for (int off = 1; off < 64; off <<= 1) { s += __shfl_xor(s, off); s2 += __shfl_xor(s2, off); }
        mu = s * inv_count;
        rstd = rsqrtf(s2 * inv_count - mu * mu + EPS);
        alpha = asl[0];
    }

    int gmr = m0 + srow;
    bool inm = (gmr < M);
    const unsigned short* xrow = Xin + (size_t)gmr * 32 + sblk * 8;
    unsigned short* xdst = &xs[0][srow * 32 + ((sblk ^ (srow & 3)) * 8)];

    auto stage = [&](int k0, int buf) {
        bf16x8 xv = {};
        if (inm) {
            bf16x8 u = *reinterpret_cast<const bf16x8*>(xrow + (size_t)(k0 >> 5) * N_NODES * 32);
            if (TRANSFORM) {
                int f0 = k0 + sblk * 8;
                float ga[8], ba[8];
                *reinterpret_cast<float4*>(&ga[0]) = *reinterpret_cast<const float4*>(gw + f0);
                *reinterpret_cast<float4*>(&ga[4]) = *reinterpret_cast<const float4*>(gw + f0 + 4);
                *reinterpret_cast<float4*>(&ba[0]) = *reinterpret_cast<const float4*>(bw + f0);
                *reinterpret_cast<float4*>(&ba[4]) = *reinterpret_cast<const float4*>(bw + f0 + 4);
                #pragma unroll
                for (int i = 0; i < 8; ++i) {
                    float A = rstd * ga[i];
                    float B = ba[i] - mu * A;
                    float v = fmaf(b2f((unsigned short)u[i]), A, B);
                    v = fmaf(fminf(v, 0.f), alpha - 1.0f, v);
                    xv[i] = (short)f2b(v);
                }
            } else {
                xv = u;
            }
        }
        *reinterpret_cast<bf16x8*>(xdst + buf * (64 * 32)) = xv;
    };

    stage(0, 0);
    f32x4 acc[4][FR_N] = {};
    int nsteps = K / 32;
    for (int s = 0; s < nsteps; ++s) {
        __syncthreads();
        int k0 = s * 32;
        if (s + 1 < nsteps) stage(k0 + 32, (s + 1) & 1);
        bf16x8 b[FR_N];
        #pragma unroll
        for (int j = 0; j < FR_N; ++j)
            b[j] = *reinterpret_cast<const bf16x8*>(
                Wb + (size_t)(colbase + j * 16 + l16) * K + k0 + kg * 8);
        const unsigned short* xbuf = xs[s & 1];
        bf16x8 a[4];
        #pragma unroll
        for (int i = 0; i < 4; ++i) {
            int ar = i * 16 + l16;
            a[i] = *reinterpret_cast<const bf16x8*>(xbuf + ar * 32 + ((kg ^ (ar & 3)) * 8));
        }
        #pragma unroll
        for (int i = 0; i < 4; ++i)
            #pragma unroll
            for (int j = 0; j < FR_N; ++j)
                acc[i][j] = __builtin_amdgcn_mfma_f32_16x16x32_bf16(b[j], a[i], acc[i][j], 0, 0, 0);
    }

    float bsel[FR_N][4];
    if (ADD_BIAS) {
        #pragma unroll
        for (int j = 0; j < FR_N; ++j)
            *reinterpret_cast<float4*>(bsel[j]) =
                *reinterpret_cast<const float4*>(bias + colbase + j * 16 + kg * 4);
    }
    float s = 0.f, s2 = 0.f;
    #pragma unroll
    for (int i = 0; i < 4; ++i) {
        int row = m0 + i * 16 + l16;
        if (row < M) {
            #pragma unroll
            for (int j = 0; j < FR_N; ++j) {
                int col = colbase + j * 16 + kg * 4;
                us4 o;
                #pragma unroll
                for (int r = 0; r < 4; ++r) {
                    float v = acc[i][j][r] + (ADD_BIAS ? bsel[j][r] : 0.f);
                    if (FUSE_RED) { s += v; s2 += v * v; }
                    o[r] = f2b(v);
                }
                *reinterpret_cast<us4*>(
                    Hout + ((size_t)(col >> 5) * N_NODES + row) * 32 + (col & 31)) = o;
            }
        }
    }
    if (FUSE_RED) {
        #pragma unroll
        for (int off = 1; off < 64; off <<= 1) { s += __shfl_xor(s, off); s2 += __shfl_xor(s2, off); }
        if (lane == 0) {
            int bkt = (blockIdx.x & (RED_BUCKETS - 1)) * 16;
            atomicAdd(&redout[bkt], s);
            atomicAdd(&redout[bkt + 1], s2);
        }
    }
}

// ---------------- aggregation: sorted domain, XCD-pinned chunk, VALU-lean pipeline ----------
// 4 lanes/node (16B each), 64 nodes/block. Self-loop peeled (load issued first, consumed
// after prologue). Edge loop unroll x2, rows 2 ahead, epack 4 ahead (padded: no clamps).
// w-extract = 1 AND; validity = 1 cndmask; 32-bit saddr offsets; f32x2 packed FMA.

template<int COLS, bool ADD_BIAS, bool FUSE_RED>
__device__ __forceinline__ void agg_body(
    const unsigned short* __restrict__ Hb, const int* __restrict__ soff,
    const unsigned int* __restrict__ epack, const float* __restrict__ dinv2s,
    const float* __restrict__ bias, unsigned short* __restrict__ Y,
    float* __restrict__ red) {
    constexpr int CHUNKS = COLS / 32;
    int chunk = blockIdx.x % CHUNKS;
    int nodeblk = blockIdx.x / CHUNKS;
    int t = threadIdx.x;
    int p = nodeblk * 64 + (t >> 2);
    unsigned rl8 = (unsigned)(t & 3) * 8;
    bool active = p < N_NODES;
    int pc = active ? p : (N_NODES - 1);
    const unsigned short* HbC = Hb + (size_t)chunk * N_NODES * 32;  // uniform base
    int s0 = soff[pc];
    unsigned s1 = (unsigned)(active ? soff[pc + 1] : s0);
    float wself = active ? dinv2s[pc] : 0.f;
    int cnt = (int)s1 - s0;
    int nmax = cnt;
    #pragma unroll
    for (int off = 1; off < 64; off <<= 1) nmax = max(nmax, __shfl_xor(nmax, off));

    auto wof = [&](unsigned u, unsigned e) -> float {
        float w = __uint_as_float(u & 0xffff0000u);   // hi bf16 as f32: 1 AND
        return (e < s1) ? w : 0.f;
    };
    auto offof = [&](unsigned u) -> unsigned {
        return ((u & 0xffffu) << 5) + rl8;            // element offset, <= 1.6M
    };
    auto rowld = [&](unsigned off) -> bf16x8 {
        return *reinterpret_cast<const bf16x8*>(HbC + off);
    };

    f32x2 acc2[4] = {};
    auto accum = [&](float w, bf16x8 v) {
        u32x4 vu = __builtin_bit_cast(u32x4, v);
        f32x2 w2 = {w, w};
        #pragma unroll
        for (int q = 0; q < 4; ++q) {
            f32x2 pv;
            pv.x = __uint_as_float(vu[q] << 16);
            pv.y = __uint_as_float(vu[q] & 0xffff0000u);
            acc2[q] += w2 * pv;                        // v_pk_fma_f32
        }
    };

    unsigned e0 = (unsigned)s0;
    bf16x8 vself = rowld(((unsigned)pc << 5) + rl8);   // issue self row first
    unsigned ua = epack[e0], ub = epack[e0 + 1];       // prologue epack (padded: safe)
    float w0 = wof(ua, e0), w1 = wof(ub, e0 + 1);
    bf16x8 v0 = rowld(offof(ua)), v1 = rowld(offof(ub));
    unsigned uc = epack[e0 + 2], ud = epack[e0 + 3];
    accum(wself, vself);                               // self consumed under edge issue
    for (int i = 0; i < nmax; i += 2) {
        float w2 = wof(uc, e0 + i + 2), w3 = wof(ud, e0 + i + 3);
        bf16x8 v2 = rowld(offof(uc)), v3 = rowld(offof(ud));   // rows 2 slots ahead
        unsigned ue = epack[e0 + i + 4], uf = epack[e0 + i + 5];
        accum(w0, v0);
        accum(w1, v1);
        w0 = w2; v0 = v2; w1 = w3; v1 = v3; uc = ue; ud = uf;
    }

    if (ADD_BIAS && active) {
        #pragma unroll
        for (int q = 0; q < 4; ++q) {
            acc2[q].x += bias[chunk * 32 + rl8 + 2 * q];
            acc2[q].y += bias[chunk * 32 + rl8 + 2 * q + 1];
        }
    }
    if (FUSE_RED) {
        float s = 0.f, s2 = 0.f;
        #pragma unroll
        for (int q = 0; q < 4; ++q) {
            s += acc2[q].x + acc2[q].y;
            s2 += acc2[q].x * acc2[q].x + acc2[q].y * acc2[q].y;
        }
        #pragma unroll
        for (int off = 1; off < 64; off <<= 1) { s += __shfl_xor(s, off); s2 += __shfl_xor(s2, off); }
        if ((t & 63) == 0) {
            int bkt = (blockIdx.x & (RED_BUCKETS - 1)) * 16;
            atomicAdd(&red[bkt], s);
            atomicAdd(&red[bkt + 1], s2);
        }
    }
    if (active) {
        bf16x8 o;
        #pragma unroll
        for (int q = 0; q < 4; ++q) {
            o[2 * q] = (short)f2b(acc2[q].x);
            o[2 * q + 1] = (short)f2b(acc2[q].y);
        }
        __builtin_nontemporal_store(
            o, reinterpret_cast<bf16x8*>(Y + ((size_t)chunk * N_NODES + p) * 32 + rl8));
    }
}

// ---------------- distinctly-named wrappers ----------------

__global__ __launch_bounds__(256) void gemm_l0(const unsigned short* X, const unsigned short* W,
                                               const float* bias, float* redout,
                                               unsigned short* H, int M, int K, float ic) {
    gemm_body<256, false, true, true>(X, W, bias, nullptr, nullptr, nullptr, nullptr, redout, H, M, K, ic);
}
__global__ __launch_bounds__(256) void gemm_l1(const unsigned short* X, const unsigned short* W,
                                               const float* redin, const float* gw, const float* bw,
                                               const float* asl, unsigned short* H, int M, int K, float ic) {
    gemm_body<256, true, false, false>(X, W, nullptr, redin, gw, bw, asl, nullptr, H, M, K, ic);
}
__global__ __launch_bounds__(256) void gemm_l2(const unsigned short* X, const unsigned short* W,
                                               const float* redin, const float* gw, const float* bw,
                                               const float* asl, unsigned short* H, int M, int K, float ic) {
    gemm_body<128, true, false, false>(X, W, nullptr, redin, gw, bw, asl, nullptr, H, M, K, ic);
}
__global__ void agg_l0(const unsigned short* Hb, const int* soff, const unsigned int* ep,
                       const float* dinv2s, unsigned short* Y) {
    agg_body<128, false, false>(Hb, soff, ep, dinv2s, nullptr, Y, nullptr);
}
__global__ void agg_l1(const unsigned short* Hb, const int* soff, const unsigned int* ep,
                       const float* dinv2s, const float* bias, unsigned short* Y, float* red) {
    agg_body<256, true, true>(Hb, soff, ep, dinv2s, bias, Y, red);
}
__global__ void agg_l2(const unsigned short* Hb, const int* soff, const unsigned int* ep,
                       const float* dinv2s, const float* bias, unsigned short* Y, float* red) {
    agg_body<128, true, true>(Hb, soff, ep, dinv2s, bias, Y, red);
}

// ---------------- final LN + PReLU: original-domain loop, gathered sorted reads ----------------

__global__ void norm_final(const unsigned short* __restrict__ Yb, const int* __restrict__ iperm,
                           const float* __restrict__ red,
                           const float* __restrict__ g, const float* __restrict__ be,
                           const float* __restrict__ a, float* __restrict__ X,
                           float inv_count) {
    int lane = threadIdx.x & 63;
    float s = red[lane * 16], s2 = red[lane * 16 + 1];
    #pragma unroll
    for (int off = 1; off < 64; off <<= 1) { s += __shfl_xor(s, off); s2 += __shfl_xor(s2, off); }
    float mu = s * inv_count;
    float rstd = rsqrtf(s2 * inv_count - mu * mu + EPS);
    float alpha = a[0];
    int total = N_NODES * 16;
    for (int i = blockIdx.x * blockDim.x + threadIdx.x; i < total; i += gridDim.x * blockDim.x) {
        int n = i >> 4;
        int r = i & 15;
        int f0 = r * 8;
        int p = iperm[n];
        bf16x8 v = *reinterpret_cast<const bf16x8*>(
            Yb + ((size_t)(f0 >> 5) * N_NODES + p) * 32 + (f0 & 31));
        float o[8];
        #pragma unroll
        for (int j = 0; j < 8; ++j) {
            float t = (b2f((unsigned short)v[j]) - mu) * rstd * g[f0 + j] + be[f0 + j];
            o[j] = t >= 0.f ? t : alpha * t;
        }
        float* xp = X + (size_t)n * 128 + f0;
        *reinterpret_cast<float4*>(xp) = make_float4(o[0], o[1], o[2], o[3]);
        *reinterpret_cast<float4*>(xp + 4) = make_float4(o[4], o[5], o[6], o[7]);
    }
}

// ---------------- launch ----------------

extern "C" void kernel_launch(void* const* d_in, const int* in_sizes, int n_in,
                              void* d_out, int out_size, void* d_ws, size_t ws_size,
                              hipStream_t stream) {
    const float* x0 = (const float*)d_in[0];
    const int* ei = (const int*)d_in[1];
    const float* W[3] = {(const float*)d_in[2], (const float*)d_in[7], (const float*)d_in[12]};
    const float* bb[3] = {(const float*)d_in[3], (const float*)d_in[8], (const float*)d_in[13]};
    const float* gg[3] = {(const float*)d_in[4], (const float*)d_in[9], (const float*)d_in[14]};
    const float* be[3] = {(const float*)d_in[5], (const float*)d_in[10], (const float*)d_in[15]};
    const float* aa[3] = {(const float*)d_in[6], (const float*)d_in[11], (const float*)d_in[16]};

    char* ws = (char*)d_ws;
    size_t o = 0;
    auto alloc = [&](size_t bytes) {
        void* p = ws + o;
        o = (o + bytes + 255) & ~(size_t)255;
        return p;
    };
    int* deg = (int*)alloc(N_NODES * 4);
    int* fill = (int*)alloc(N_NODES * 4);
    int* soff = (int*)alloc((N_NODES + 1) * 4);
    unsigned int* epack = (unsigned int*)alloc((size_t)(N_EDGES + 64) * 4);
    float* dinv = (float*)alloc(N_NODES * 4);
    float* dinv2s = (float*)alloc(N_NODES * 4);
    int* hist = (int*)alloc(256 * 4);
    int* binpre = (int*)alloc(256 * 4);
    int* binfill = (int*)alloc(256 * 4);
    int* edgepre = (int*)alloc(256 * 4);
    int* perm = (int*)alloc(N_NODES * 4);
    int* iperm = (int*)alloc(N_NODES * 4);
    float* red = (float*)alloc(3 * RED_FLOATS_PER_LAYER * 4);
    unsigned short* Wb0 = (unsigned short*)alloc(256 * 128 * 2);
    unsigned short* Wb1 = (unsigned short*)alloc(256 * 256 * 2);
    unsigned short* Wb2 = (unsigned short*)alloc(128 * 256 * 2);
    unsigned short* xb = (unsigned short*)alloc((size_t)N_NODES * 128 * 2);
    unsigned short* hb = (unsigned short*)alloc((size_t)N_NODES * 256 * 2);
    unsigned short* yb = (unsigned short*)alloc((size_t)N_NODES * 256 * 2);

    const int* e_src = ei;
    const int* e_dst = ei + N_EDGES;
    int nb = (N_NODES + 255) / 256;  // 196

    prep_kernel<<<nb, 256, 0, stream>>>(W[0], W[1], W[2], Wb0, Wb1, Wb2, deg, fill, hist, red,
                                        epack);
    count_kernel<<<2048, 256, 0, stream>>>(e_dst, deg, N_EDGES);
    histo_kernel<<<nb, 256, 0, stream>>>(deg, dinv, hist, N_NODES);
    scan2_kernel<<<1, 256, 0, stream>>>(hist, binpre, binfill, edgepre);
    permute_kernel<<<nb, 256, 0, stream>>>(deg, dinv, binpre, binfill, edgepre,
                                           perm, iperm, dinv2s, soff, N_NODES);
    convert_x_kernel<<<(CV_NX + 255) / 256, 256, 0, stream>>>(x0, perm, xb);
    scatter_kernel<<<2048, 256, 0, stream>>>(e_src, e_dst, soff, fill, dinv, iperm,
                                             epack, N_EDGES);

    int gm = (N_NODES + 63) / 64;  // 782
    float ic256 = 1.0f / (N_NODES * 256.0f);
    float ic128 = 1.0f / (N_NODES * 128.0f);

    // ---- Layer 0 ----
    agg_l0<<<gm * 4, 256, 0, stream>>>(xb, soff, epack, dinv2s, hb);
    gemm_l0<<<gm, 256, 0, stream>>>(hb, Wb0, bb[0], red + 0, yb, N_NODES, 128, ic256);

    // ---- Layer 1 ----
    gemm_l1<<<gm, 256, 0, stream>>>(yb, Wb1, red + 0, gg[0], be[0], aa[0], hb, N_NODES, 256, ic256);
    agg_l1<<<gm * 8, 256, 0, stream>>>(hb, soff, epack, dinv2s, bb[1], yb,
                                       red + RED_FLOATS_PER_LAYER);

    // ---- Layer 2 ----
    gemm_l2<<<gm, 256, 0, stream>>>(yb, Wb2, red + RED_FLOATS_PER_LAYER, gg[1], be[1], aa[1], hb,
                                    N_NODES, 256, ic256);
    agg_l2<<<gm * 4, 256, 0, stream>>>(hb, soff, epack, dinv2s, bb[2], yb,
                                       red + 2 * RED_FLOATS_PER_LAYER);

    // ---- final LN + PReLU -> d_out f32 (original domain) ----
    norm_final<<<2048, 256, 0, stream>>>(yb, iperm, red + 2 * RED_FLOATS_PER_LAYER,
                                         gg[2], be[2], aa[2], (float*)d_out, ic128);
}